// Round 1
// baseline (475.195 us; speedup 1.0000x reference)
//
#include <hip/hip_runtime.h>

#define N_NODES 100000
#define N_EDGES 1600000
#define IN_DIM  64
#define HID     128
#define ROWS    32
#define BN_EPS  1e-5f

// ---------------- scatter-add: agg[dst[e]] += h[src[e]] ----------------
// one edge per 64-lane wave, lane k handles feature k (coalesced 256B per wave)
__global__ __launch_bounds__(256) void scatter_kernel(
    const float* __restrict__ h, const int* __restrict__ src,
    const int* __restrict__ dst, float* __restrict__ agg, int n_edges)
{
    long long t = (long long)blockIdx.x * blockDim.x + threadIdx.x;
    int e = (int)(t >> 6);
    int k = (int)(t & 63);
    if (e < n_edges) {
        int s = src[e];
        int d = dst[e];
        atomicAdd(&agg[(size_t)d * IN_DIM + k], h[(size_t)s * IN_DIM + k]);
    }
}

// ---------------- GEMM (agg @ W + b) with fused per-column stats ----------------
// block: 256 threads, 32 rows x 128 cols tile. thread = 4 rows x 4 cols.
__global__ __launch_bounds__(256) void gemm_stats_kernel(
    const float* __restrict__ agg, const float* __restrict__ W,
    const float* __restrict__ bias, float* __restrict__ z,
    float* __restrict__ gsum, float* __restrict__ gsq)
{
    __shared__ float Ws[IN_DIM][HID];   // 32 KB
    __shared__ float As[ROWS][IN_DIM];  // 8 KB
    __shared__ float s_sum[HID];
    __shared__ float s_sq[HID];

    const int tid = threadIdx.x;

    // stage W (8192 floats) coalesced
    {
        const float4* s4 = (const float4*)W;
        float4* d4 = (float4*)&Ws[0][0];
#pragma unroll
        for (int i = 0; i < (IN_DIM * HID / 4) / 256; ++i)
            d4[tid + i * 256] = s4[tid + i * 256];
    }
    // stage 32 rows of agg (2048 floats)
    const int row0 = blockIdx.x * ROWS;
    {
        const float4* s4 = (const float4*)(agg + (size_t)row0 * IN_DIM);
        float4* d4 = (float4*)&As[0][0];
#pragma unroll
        for (int i = 0; i < (ROWS * IN_DIM / 4) / 256; ++i)
            d4[tid + i * 256] = s4[tid + i * 256];
    }
    if (tid < HID) { s_sum[tid] = 0.f; s_sq[tid] = 0.f; }
    __syncthreads();

    const int col = tid & 31;        // cols col, col+32, col+64, col+96
    const int r0  = (tid >> 5) * 4;  // 4 consecutive rows

    float acc[4][4];
#pragma unroll
    for (int i = 0; i < 4; i++)
#pragma unroll
        for (int j = 0; j < 4; j++) acc[i][j] = 0.f;

#pragma unroll 8
    for (int k = 0; k < IN_DIM; k++) {
        float w[4], a[4];
#pragma unroll
        for (int j = 0; j < 4; j++) w[j] = Ws[k][col + 32 * j];
#pragma unroll
        for (int i = 0; i < 4; i++) a[i] = As[r0 + i][k];
#pragma unroll
        for (int i = 0; i < 4; i++)
#pragma unroll
            for (int j = 0; j < 4; j++) acc[i][j] += a[i] * w[j];
    }

    float lsum[4] = {0, 0, 0, 0}, lsq[4] = {0, 0, 0, 0};
#pragma unroll
    for (int i = 0; i < 4; i++) {
        const int row = row0 + r0 + i;
#pragma unroll
        for (int j = 0; j < 4; j++) {
            float v = acc[i][j] + bias[col + 32 * j];
            z[(size_t)row * HID + col + 32 * j] = v;
            lsum[j] += v;
            lsq[j]  += v * v;
        }
    }
#pragma unroll
    for (int j = 0; j < 4; j++) {
        atomicAdd(&s_sum[col + 32 * j], lsum[j]);
        atomicAdd(&s_sq [col + 32 * j], lsq[j]);
    }
    __syncthreads();
    if (tid < HID) {
        atomicAdd(&gsum[tid], s_sum[tid]);
        atomicAdd(&gsq [tid], s_sq[tid]);
    }
}

// ---------------- finalize: per-column scale/shift ----------------
__global__ void finalize_kernel(const float* __restrict__ gsum,
                                const float* __restrict__ gsq,
                                const float* __restrict__ gamma,
                                const float* __restrict__ beta,
                                float* __restrict__ scale,
                                float* __restrict__ shift, float inv_n)
{
    int c = threadIdx.x;
    float mean = gsum[c] * inv_n;
    float var  = gsq[c] * inv_n - mean * mean;
    float inv  = rsqrtf(var + BN_EPS);
    float sc   = gamma[c] * inv;
    scale[c] = sc;
    shift[c] = beta[c] - mean * sc;
}

// ---------------- normalize in place (d_out) ----------------
__global__ __launch_bounds__(256) void norm_kernel(
    float* __restrict__ z, const float* __restrict__ scale,
    const float* __restrict__ shift, int total4)
{
    __shared__ float sS[HID], sH[HID];
    const int tid = threadIdx.x;
    if (tid < HID) { sS[tid] = scale[tid]; sH[tid] = shift[tid]; }
    __syncthreads();

    float4* z4 = (float4*)z;
    for (int i = blockIdx.x * blockDim.x + tid; i < total4;
         i += gridDim.x * blockDim.x) {
        float4 v = z4[i];
        int c = (i & 31) * 4;  // column of v.x (HID=128 -> 32 float4 per row)
        v.x = v.x * sS[c + 0] + sH[c + 0];
        v.y = v.y * sS[c + 1] + sH[c + 1];
        v.z = v.z * sS[c + 2] + sH[c + 2];
        v.w = v.w * sS[c + 3] + sH[c + 3];
        z4[i] = v;
    }
}

extern "C" void kernel_launch(void* const* d_in, const int* in_sizes, int n_in,
                              void* d_out, int out_size, void* d_ws, size_t ws_size,
                              hipStream_t stream)
{
    const float* h     = (const float*)d_in[0];
    const int*   src   = (const int*)d_in[1];
    const int*   dst   = (const int*)d_in[2];
    const float* W     = (const float*)d_in[3];
    const float* b     = (const float*)d_in[4];
    const float* gamma = (const float*)d_in[5];
    const float* beta  = (const float*)d_in[6];

    float* z = (float*)d_out;  // staged z, then normalized in place

    float* agg   = (float*)d_ws;                       // N_NODES*IN_DIM floats
    float* gsum  = agg + (size_t)N_NODES * IN_DIM;     // HID
    float* gsq   = gsum + HID;                         // HID
    float* scale = gsq + HID;                          // HID
    float* shift = scale + HID;                        // HID

    // zero agg + stats (contiguous)
    hipMemsetAsync(agg, 0, ((size_t)N_NODES * IN_DIM + 2 * HID) * sizeof(float),
                   stream);

    {
        long long total = (long long)N_EDGES * 64;
        int blocks = (int)((total + 255) / 256);
        scatter_kernel<<<blocks, 256, 0, stream>>>(h, src, dst, agg, N_EDGES);
    }
    gemm_stats_kernel<<<N_NODES / ROWS, 256, 0, stream>>>(agg, W, b, z, gsum, gsq);
    finalize_kernel<<<1, HID, 0, stream>>>(gsum, gsq, gamma, beta, scale, shift,
                                           1.0f / (float)N_NODES);
    norm_kernel<<<2048, 256, 0, stream>>>(z, scale, shift, N_NODES * HID / 4);
}

// Round 2
// 369.376 us; speedup vs baseline: 1.2865x; 1.2865x over previous
//
#include <hip/hip_runtime.h>

#define N_NODES 100000
#define N_EDGES 1600000
#define IN_DIM  64
#define HID     128
#define ROWS    32
#define BN_EPS  1e-5f

#define HIST_PAD 100352          // 98 blocks * 1024
#define SCAN_BLOCKS 98           // ceil(100000/1024)

// ---------------- 1. histogram of dst ----------------
__global__ __launch_bounds__(256) void hist_kernel(const int* __restrict__ dst,
                                                   int* __restrict__ hist)
{
    int i = blockIdx.x * blockDim.x + threadIdx.x;
    if (i < N_EDGES / 4) {
        int4 d = ((const int4*)dst)[i];
        atomicAdd(&hist[d.x], 1);
        atomicAdd(&hist[d.y], 1);
        atomicAdd(&hist[d.z], 1);
        atomicAdd(&hist[d.w], 1);
    }
}

// ---------------- 2a. per-block (1024-elem) sums ----------------
__global__ __launch_bounds__(256) void scanA_kernel(const int* __restrict__ hist,
                                                    int* __restrict__ blockSums)
{
    __shared__ int lds[256];
    int t = threadIdx.x;
    int4 v = ((const int4*)hist)[blockIdx.x * 256 + t];
    lds[t] = v.x + v.y + v.z + v.w;
    __syncthreads();
    for (int off = 128; off > 0; off >>= 1) {
        if (t < off) lds[t] += lds[t + off];
        __syncthreads();
    }
    if (t == 0) blockSums[blockIdx.x] = lds[0];
}

// ---------------- 2b. scan the 98 block sums (1 block) ----------------
__global__ __launch_bounds__(128) void scanB_kernel(const int* __restrict__ blockSums,
                                                    int* __restrict__ blockOff)
{
    __shared__ int lds[128];
    int t = threadIdx.x;
    int v = (t < SCAN_BLOCKS) ? blockSums[t] : 0;
    lds[t] = v;
    __syncthreads();
    for (int off = 1; off < 128; off <<= 1) {
        int u = (t >= off) ? lds[t - off] : 0;
        __syncthreads();
        lds[t] += u;
        __syncthreads();
    }
    if (t < SCAN_BLOCKS) blockOff[t] = lds[t] - v;  // exclusive
}

// ---------------- 2c. per-block exclusive scan -> offsets, cursor ----------------
// cursor may alias hist (each element read-then-written by the same thread).
__global__ __launch_bounds__(256) void scanC_kernel(const int* __restrict__ hist,
                                                    const int* __restrict__ blockOff,
                                                    int* __restrict__ offsets,
                                                    int* __restrict__ cursor)
{
    __shared__ int lds[256];
    int t = threadIdx.x;
    int idx = blockIdx.x * 256 + t;
    int4 v = ((const int4*)hist)[idx];
    int tsum = v.x + v.y + v.z + v.w;
    lds[t] = tsum;
    __syncthreads();
    for (int off = 1; off < 256; off <<= 1) {
        int u = (t >= off) ? lds[t - off] : 0;
        __syncthreads();
        lds[t] += u;
        __syncthreads();
    }
    int base = blockOff[blockIdx.x] + lds[t] - tsum;  // exclusive across grid
    int i0 = idx * 4;
    int e0 = base;
    int e1 = e0 + v.x;
    int e2 = e1 + v.y;
    int e3 = e2 + v.z;
    offsets[i0 + 0] = e0; offsets[i0 + 1] = e1;
    offsets[i0 + 2] = e2; offsets[i0 + 3] = e3;
    cursor[i0 + 0] = e0; cursor[i0 + 1] = e1;
    cursor[i0 + 2] = e2; cursor[i0 + 3] = e3;
}

// ---------------- 3. place src values into dst-sorted buckets ----------------
__global__ __launch_bounds__(256) void place_kernel(const int* __restrict__ src,
                                                    const int* __restrict__ dst,
                                                    int* __restrict__ cursor,
                                                    int* __restrict__ sortedSrc)
{
    int e = blockIdx.x * blockDim.x + threadIdx.x;
    if (e < N_EDGES) {
        int d = dst[e];
        int pos = atomicAdd(&cursor[d], 1);
        sortedSrc[pos] = src[e];
    }
}

// ---------------- 4. aggregate: one wave per node, lane = feature ----------------
__global__ __launch_bounds__(256) void aggregate_kernel(
    const float* __restrict__ h, const int* __restrict__ sortedSrc,
    const int* __restrict__ offsets, float* __restrict__ agg)
{
    int wave = (blockIdx.x * 256 + threadIdx.x) >> 6;
    int lane = threadIdx.x & 63;
    if (wave >= N_NODES) return;
    int beg = offsets[wave];
    int end = offsets[wave + 1];
    float acc = 0.f;
    for (int i = beg; i < end; i += 64) {
        int cnt = end - i; if (cnt > 64) cnt = 64;
        int sv = (lane < cnt) ? sortedSrc[i + lane] : 0;
        int j = 0;
        for (; j + 4 <= cnt; j += 4) {
            int s0 = __shfl(sv, j + 0);
            int s1 = __shfl(sv, j + 1);
            int s2 = __shfl(sv, j + 2);
            int s3 = __shfl(sv, j + 3);
            float v0 = h[s0 * IN_DIM + lane];
            float v1 = h[s1 * IN_DIM + lane];
            float v2 = h[s2 * IN_DIM + lane];
            float v3 = h[s3 * IN_DIM + lane];
            acc += v0; acc += v1; acc += v2; acc += v3;
        }
        for (; j < cnt; ++j) {
            int s = __shfl(sv, j);
            acc += h[s * IN_DIM + lane];
        }
    }
    agg[(size_t)wave * IN_DIM + lane] = acc;
}

// ---------------- 5. GEMM (agg @ W + b) with fused per-column stats ----------------
__global__ __launch_bounds__(256) void gemm_stats_kernel(
    const float* __restrict__ agg, const float* __restrict__ W,
    const float* __restrict__ bias, float* __restrict__ z,
    float* __restrict__ gsum, float* __restrict__ gsq)
{
    __shared__ float Ws[IN_DIM][HID];   // 32 KB
    __shared__ float As[ROWS][IN_DIM];  // 8 KB
    __shared__ float s_sum[HID];
    __shared__ float s_sq[HID];

    const int tid = threadIdx.x;

    {
        const float4* s4 = (const float4*)W;
        float4* d4 = (float4*)&Ws[0][0];
#pragma unroll
        for (int i = 0; i < (IN_DIM * HID / 4) / 256; ++i)
            d4[tid + i * 256] = s4[tid + i * 256];
    }
    const int row0 = blockIdx.x * ROWS;
    {
        const float4* s4 = (const float4*)(agg + (size_t)row0 * IN_DIM);
        float4* d4 = (float4*)&As[0][0];
#pragma unroll
        for (int i = 0; i < (ROWS * IN_DIM / 4) / 256; ++i)
            d4[tid + i * 256] = s4[tid + i * 256];
    }
    if (tid < HID) { s_sum[tid] = 0.f; s_sq[tid] = 0.f; }
    __syncthreads();

    const int col = tid & 31;
    const int r0  = (tid >> 5) * 4;

    float acc[4][4];
#pragma unroll
    for (int i = 0; i < 4; i++)
#pragma unroll
        for (int j = 0; j < 4; j++) acc[i][j] = 0.f;

#pragma unroll 8
    for (int k = 0; k < IN_DIM; k++) {
        float w[4], a[4];
#pragma unroll
        for (int j = 0; j < 4; j++) w[j] = Ws[k][col + 32 * j];
#pragma unroll
        for (int i = 0; i < 4; i++) a[i] = As[r0 + i][k];
#pragma unroll
        for (int i = 0; i < 4; i++)
#pragma unroll
            for (int j = 0; j < 4; j++) acc[i][j] += a[i] * w[j];
    }

    float lsum[4] = {0, 0, 0, 0}, lsq[4] = {0, 0, 0, 0};
#pragma unroll
    for (int i = 0; i < 4; i++) {
        const int row = row0 + r0 + i;
#pragma unroll
        for (int j = 0; j < 4; j++) {
            float v = acc[i][j] + bias[col + 32 * j];
            z[(size_t)row * HID + col + 32 * j] = v;
            lsum[j] += v;
            lsq[j]  += v * v;
        }
    }
#pragma unroll
    for (int j = 0; j < 4; j++) {
        atomicAdd(&s_sum[col + 32 * j], lsum[j]);
        atomicAdd(&s_sq [col + 32 * j], lsq[j]);
    }
    __syncthreads();
    if (tid < HID) {
        atomicAdd(&gsum[tid], s_sum[tid]);
        atomicAdd(&gsq [tid], s_sq[tid]);
    }
}

// ---------------- 6. finalize ----------------
__global__ void finalize_kernel(const float* __restrict__ gsum,
                                const float* __restrict__ gsq,
                                const float* __restrict__ gamma,
                                const float* __restrict__ beta,
                                float* __restrict__ scale,
                                float* __restrict__ shift, float inv_n)
{
    int c = threadIdx.x;
    float mean = gsum[c] * inv_n;
    float var  = gsq[c] * inv_n - mean * mean;
    float inv  = rsqrtf(var + BN_EPS);
    float sc   = gamma[c] * inv;
    scale[c] = sc;
    shift[c] = beta[c] - mean * sc;
}

// ---------------- 7. normalize in place ----------------
__global__ __launch_bounds__(256) void norm_kernel(
    float* __restrict__ z, const float* __restrict__ scale,
    const float* __restrict__ shift, int total4)
{
    __shared__ float sS[HID], sH[HID];
    const int tid = threadIdx.x;
    if (tid < HID) { sS[tid] = scale[tid]; sH[tid] = shift[tid]; }
    __syncthreads();

    float4* z4 = (float4*)z;
    for (int i = blockIdx.x * blockDim.x + tid; i < total4;
         i += gridDim.x * blockDim.x) {
        float4 v = z4[i];
        int c = (i & 31) * 4;
        v.x = v.x * sS[c + 0] + sH[c + 0];
        v.y = v.y * sS[c + 1] + sH[c + 1];
        v.z = v.z * sS[c + 2] + sH[c + 2];
        v.w = v.w * sS[c + 3] + sH[c + 3];
        z4[i] = v;
    }
}

extern "C" void kernel_launch(void* const* d_in, const int* in_sizes, int n_in,
                              void* d_out, int out_size, void* d_ws, size_t ws_size,
                              hipStream_t stream)
{
    const float* h     = (const float*)d_in[0];
    const int*   src   = (const int*)d_in[1];
    const int*   dst   = (const int*)d_in[2];
    const float* W     = (const float*)d_in[3];
    const float* b     = (const float*)d_in[4];
    const float* gamma = (const float*)d_in[5];
    const float* beta  = (const float*)d_in[6];

    float* z = (float*)d_out;

    // workspace layout (ints unless noted)
    int* hist      = (int*)d_ws;              // HIST_PAD, also reused as cursor
    int* blockSums = hist + HIST_PAD;         // 128
    int* blockOff  = blockSums + 128;         // 128
    int* offsets   = blockOff + 128;          // HIST_PAD (+1 usable: offsets[N_NODES])
    int* sortedSrc = offsets + HIST_PAD;      // N_EDGES
    float* agg     = (float*)(sortedSrc + N_EDGES);      // N_NODES*IN_DIM
    float* gsum    = agg + (size_t)N_NODES * IN_DIM;     // HID
    float* gsq     = gsum + HID;                         // HID
    float* scale   = gsq + HID;                          // HID
    float* shift   = scale + HID;                        // HID

    int* cursor = hist;  // alias: scanC rewrites hist slots it has already read

    hipMemsetAsync(hist, 0, HIST_PAD * sizeof(int), stream);
    hipMemsetAsync(gsum, 0, 2 * HID * sizeof(float), stream);

    hist_kernel<<<(N_EDGES / 4 + 255) / 256, 256, 0, stream>>>(dst, hist);
    scanA_kernel<<<SCAN_BLOCKS, 256, 0, stream>>>(hist, blockSums);
    scanB_kernel<<<1, 128, 0, stream>>>(blockSums, blockOff);
    scanC_kernel<<<SCAN_BLOCKS, 256, 0, stream>>>(hist, blockOff, offsets, cursor);
    place_kernel<<<(N_EDGES + 255) / 256, 256, 0, stream>>>(src, dst, cursor, sortedSrc);
    aggregate_kernel<<<(N_NODES * 64 + 255) / 256, 256, 0, stream>>>(h, sortedSrc,
                                                                     offsets, agg);
    gemm_stats_kernel<<<N_NODES / ROWS, 256, 0, stream>>>(agg, W, b, z, gsum, gsq);
    finalize_kernel<<<1, HID, 0, stream>>>(gsum, gsq, gamma, beta, scale, shift,
                                           1.0f / (float)N_NODES);
    norm_kernel<<<2048, 256, 0, stream>>>(z, scale, shift, N_NODES * HID / 4);
}

// Round 3
// 250.028 us; speedup vs baseline: 1.9006x; 1.4773x over previous
//
#include <hip/hip_runtime.h>

#define N_NODES 100000
#define N_EDGES 1600000
#define IN_DIM  64
#define HID     128
#define ROWS    32
#define BN_EPS  1e-5f

// two-level counting sort geometry
#define NB        782      // coarse buckets: dst>>7 (100000>>7 = 781)
#define BC_BLOCKS 196      // binning blocks, 8192 edges each
#define EPB4      2048     // int4s per binning block
#define SC_PAD    153600   // NB*BC_BLOCKS=153272 padded to 150*1024
#define SC_NBLK   150      // scan blocks over counts

// ---------------- 1. per-(bucket,block) counts via LDS histogram ----------------
__global__ __launch_bounds__(256) void binCount_kernel(const int* __restrict__ dst,
                                                       int* __restrict__ counts)
{
    __shared__ int hist[NB];
    const int t = threadIdx.x, blk = blockIdx.x;
    for (int i = t; i < NB; i += 256) hist[i] = 0;
    __syncthreads();
    const int4* d4 = (const int4*)dst;
    const int base = blk * EPB4;
#pragma unroll
    for (int it = 0; it < 8; ++it) {
        int i = base + it * 256 + t;
        if (i < N_EDGES / 4) {
            int4 v = d4[i];
            atomicAdd(&hist[v.x >> 7], 1);
            atomicAdd(&hist[v.y >> 7], 1);
            atomicAdd(&hist[v.z >> 7], 1);
            atomicAdd(&hist[v.w >> 7], 1);
        }
    }
    __syncthreads();
    for (int i = t; i < NB; i += 256) counts[i * BC_BLOCKS + blk] = hist[i];
}

// ---------------- 2. hierarchical exclusive scan of counts ----------------
__global__ __launch_bounds__(256) void scanA_kernel(const int* __restrict__ counts,
                                                    int* __restrict__ blockSums)
{
    __shared__ int lds[256];
    int t = threadIdx.x;
    int4 v = ((const int4*)counts)[blockIdx.x * 256 + t];
    lds[t] = v.x + v.y + v.z + v.w;
    __syncthreads();
    for (int off = 128; off > 0; off >>= 1) {
        if (t < off) lds[t] += lds[t + off];
        __syncthreads();
    }
    if (t == 0) blockSums[blockIdx.x] = lds[0];
}

__global__ __launch_bounds__(256) void scanB_kernel(const int* __restrict__ blockSums,
                                                    int* __restrict__ blockOff)
{
    __shared__ int lds[256];
    int t = threadIdx.x;
    int v = (t < SC_NBLK) ? blockSums[t] : 0;
    lds[t] = v;
    __syncthreads();
    for (int off = 1; off < 256; off <<= 1) {
        int u = (t >= off) ? lds[t - off] : 0;
        __syncthreads();
        lds[t] += u;
        __syncthreads();
    }
    if (t < SC_NBLK) blockOff[t] = lds[t] - v;  // exclusive
}

__global__ __launch_bounds__(256) void scanC_kernel(const int* __restrict__ counts,
                                                    const int* __restrict__ blockOff,
                                                    int* __restrict__ scanned)
{
    __shared__ int lds[256];
    int t = threadIdx.x;
    int idx = blockIdx.x * 256 + t;
    int4 v = ((const int4*)counts)[idx];
    int tsum = v.x + v.y + v.z + v.w;
    lds[t] = tsum;
    __syncthreads();
    for (int off = 1; off < 256; off <<= 1) {
        int u = (t >= off) ? lds[t - off] : 0;
        __syncthreads();
        lds[t] += u;
        __syncthreads();
    }
    int base = blockOff[blockIdx.x] + lds[t] - tsum;
    int i0 = idx * 4;
    scanned[i0 + 0] = base;
    scanned[i0 + 1] = base + v.x;
    scanned[i0 + 2] = base + v.x + v.y;
    scanned[i0 + 3] = base + v.x + v.y + v.z;
}

// ---------------- 3. place (src,dst) into coarse buckets — LDS cursors only ----------------
__global__ __launch_bounds__(256) void binPlace_kernel(const int* __restrict__ src,
                                                       const int* __restrict__ dst,
                                                       const int* __restrict__ scanned,
                                                       int2* __restrict__ binned)
{
    __shared__ int cur[NB];
    const int t = threadIdx.x, blk = blockIdx.x;
    for (int i = t; i < NB; i += 256) cur[i] = scanned[i * BC_BLOCKS + blk];
    __syncthreads();
    const int4* d4 = (const int4*)dst;
    const int4* s4 = (const int4*)src;
    const int base = blk * EPB4;
#pragma unroll
    for (int it = 0; it < 8; ++it) {
        int i = base + it * 256 + t;
        if (i < N_EDGES / 4) {
            int4 dv = d4[i];
            int4 sv = s4[i];
            int p0 = atomicAdd(&cur[dv.x >> 7], 1); binned[p0] = make_int2(sv.x, dv.x);
            int p1 = atomicAdd(&cur[dv.y >> 7], 1); binned[p1] = make_int2(sv.y, dv.y);
            int p2 = atomicAdd(&cur[dv.z >> 7], 1); binned[p2] = make_int2(sv.z, dv.z);
            int p3 = atomicAdd(&cur[dv.w >> 7], 1); binned[p3] = make_int2(sv.w, dv.w);
        }
    }
}

// ---------------- 4. within-bucket sort by node -> CSR offsets + sortedSrc ----------------
__global__ __launch_bounds__(256) void nodeSort_kernel(const int2* __restrict__ binned,
                                                       const int* __restrict__ scanned,
                                                       int* __restrict__ sortedSrc,
                                                       int* __restrict__ offsets)
{
    __shared__ int hist[128];
    __shared__ int sc[128];
    __shared__ int cur[128];
    const int b = blockIdx.x, t = threadIdx.x;
    const int beg = scanned[b * BC_BLOCKS];
    const int end = scanned[(b + 1) * BC_BLOCKS];  // pad region yields N_EDGES for b=NB-1
    if (t < 128) hist[t] = 0;
    __syncthreads();
    for (int i = beg + t; i < end; i += 256)
        atomicAdd(&hist[binned[i].y & 127], 1);
    __syncthreads();
    int v = (t < 128) ? hist[t] : 0;
    if (t < 128) sc[t] = v;
    __syncthreads();
    for (int off = 1; off < 128; off <<= 1) {
        int u = (t < 128 && t >= off) ? sc[t - off] : 0;
        __syncthreads();
        if (t < 128) sc[t] += u;
        __syncthreads();
    }
    if (t < 128) {
        int excl = beg + sc[t] - v;
        cur[t] = excl;
        int node = (b << 7) + t;
        if (node < N_NODES) offsets[node] = excl;
    }
    if (b == NB - 1 && t == 0) offsets[N_NODES] = N_EDGES;
    __syncthreads();
    for (int i = beg + t; i < end; i += 256) {
        int2 p = binned[i];
        int pos = atomicAdd(&cur[p.y & 127], 1);
        sortedSrc[pos] = p.x;
    }
}

// ---------------- 5. aggregate: one wave per node, lane = feature ----------------
__global__ __launch_bounds__(256) void aggregate_kernel(
    const float* __restrict__ h, const int* __restrict__ sortedSrc,
    const int* __restrict__ offsets, float* __restrict__ agg)
{
    int wave = (blockIdx.x * 256 + threadIdx.x) >> 6;
    int lane = threadIdx.x & 63;
    if (wave >= N_NODES) return;
    int beg = offsets[wave];
    int end = offsets[wave + 1];
    float acc = 0.f;
    for (int i = beg; i < end; i += 64) {
        int cnt = end - i; if (cnt > 64) cnt = 64;
        int sv = (lane < cnt) ? sortedSrc[i + lane] : 0;
        int j = 0;
        for (; j + 4 <= cnt; j += 4) {
            int s0 = __shfl(sv, j + 0);
            int s1 = __shfl(sv, j + 1);
            int s2 = __shfl(sv, j + 2);
            int s3 = __shfl(sv, j + 3);
            float v0 = h[s0 * IN_DIM + lane];
            float v1 = h[s1 * IN_DIM + lane];
            float v2 = h[s2 * IN_DIM + lane];
            float v3 = h[s3 * IN_DIM + lane];
            acc += v0; acc += v1; acc += v2; acc += v3;
        }
        for (; j < cnt; ++j) {
            int s = __shfl(sv, j);
            acc += h[s * IN_DIM + lane];
        }
    }
    agg[(size_t)wave * IN_DIM + lane] = acc;
}

// ---------------- 6. GEMM (agg @ W + b) with fused per-column stats ----------------
__global__ __launch_bounds__(256) void gemm_stats_kernel(
    const float* __restrict__ agg, const float* __restrict__ W,
    const float* __restrict__ bias, float* __restrict__ z,
    float* __restrict__ gsum, float* __restrict__ gsq)
{
    __shared__ float Ws[IN_DIM][HID];
    __shared__ float As[ROWS][IN_DIM];
    __shared__ float s_sum[HID];
    __shared__ float s_sq[HID];

    const int tid = threadIdx.x;
    {
        const float4* s4 = (const float4*)W;
        float4* d4 = (float4*)&Ws[0][0];
#pragma unroll
        for (int i = 0; i < (IN_DIM * HID / 4) / 256; ++i)
            d4[tid + i * 256] = s4[tid + i * 256];
    }
    const int row0 = blockIdx.x * ROWS;
    {
        const float4* s4 = (const float4*)(agg + (size_t)row0 * IN_DIM);
        float4* d4 = (float4*)&As[0][0];
#pragma unroll
        for (int i = 0; i < (ROWS * IN_DIM / 4) / 256; ++i)
            d4[tid + i * 256] = s4[tid + i * 256];
    }
    if (tid < HID) { s_sum[tid] = 0.f; s_sq[tid] = 0.f; }
    __syncthreads();

    const int col = tid & 31;
    const int r0  = (tid >> 5) * 4;

    float acc[4][4];
#pragma unroll
    for (int i = 0; i < 4; i++)
#pragma unroll
        for (int j = 0; j < 4; j++) acc[i][j] = 0.f;

#pragma unroll 8
    for (int k = 0; k < IN_DIM; k++) {
        float w[4], a[4];
#pragma unroll
        for (int j = 0; j < 4; j++) w[j] = Ws[k][col + 32 * j];
#pragma unroll
        for (int i = 0; i < 4; i++) a[i] = As[r0 + i][k];
#pragma unroll
        for (int i = 0; i < 4; i++)
#pragma unroll
            for (int j = 0; j < 4; j++) acc[i][j] += a[i] * w[j];
    }

    float lsum[4] = {0, 0, 0, 0}, lsq[4] = {0, 0, 0, 0};
#pragma unroll
    for (int i = 0; i < 4; i++) {
        const int row = row0 + r0 + i;
#pragma unroll
        for (int j = 0; j < 4; j++) {
            float v = acc[i][j] + bias[col + 32 * j];
            z[(size_t)row * HID + col + 32 * j] = v;
            lsum[j] += v;
            lsq[j]  += v * v;
        }
    }
#pragma unroll
    for (int j = 0; j < 4; j++) {
        atomicAdd(&s_sum[col + 32 * j], lsum[j]);
        atomicAdd(&s_sq [col + 32 * j], lsq[j]);
    }
    __syncthreads();
    if (tid < HID) {
        atomicAdd(&gsum[tid], s_sum[tid]);
        atomicAdd(&gsq [tid], s_sq[tid]);
    }
}

// ---------------- 7. finalize ----------------
__global__ void finalize_kernel(const float* __restrict__ gsum,
                                const float* __restrict__ gsq,
                                const float* __restrict__ gamma,
                                const float* __restrict__ beta,
                                float* __restrict__ scale,
                                float* __restrict__ shift, float inv_n)
{
    int c = threadIdx.x;
    float mean = gsum[c] * inv_n;
    float var  = gsq[c] * inv_n - mean * mean;
    float inv  = rsqrtf(var + BN_EPS);
    float sc   = gamma[c] * inv;
    scale[c] = sc;
    shift[c] = beta[c] - mean * sc;
}

// ---------------- 8. normalize in place ----------------
__global__ __launch_bounds__(256) void norm_kernel(
    float* __restrict__ z, const float* __restrict__ scale,
    const float* __restrict__ shift, int total4)
{
    __shared__ float sS[HID], sH[HID];
    const int tid = threadIdx.x;
    if (tid < HID) { sS[tid] = scale[tid]; sH[tid] = shift[tid]; }
    __syncthreads();

    float4* z4 = (float4*)z;
    for (int i = blockIdx.x * blockDim.x + tid; i < total4;
         i += gridDim.x * blockDim.x) {
        float4 v = z4[i];
        int c = (i & 31) * 4;
        v.x = v.x * sS[c + 0] + sH[c + 0];
        v.y = v.y * sS[c + 1] + sH[c + 1];
        v.z = v.z * sS[c + 2] + sH[c + 2];
        v.w = v.w * sS[c + 3] + sH[c + 3];
        z4[i] = v;
    }
}

extern "C" void kernel_launch(void* const* d_in, const int* in_sizes, int n_in,
                              void* d_out, int out_size, void* d_ws, size_t ws_size,
                              hipStream_t stream)
{
    const float* h     = (const float*)d_in[0];
    const int*   src   = (const int*)d_in[1];
    const int*   dst   = (const int*)d_in[2];
    const float* W     = (const float*)d_in[3];
    const float* b     = (const float*)d_in[4];
    const float* gamma = (const float*)d_in[5];
    const float* beta  = (const float*)d_in[6];

    float* z = (float*)d_out;

    // ---- workspace layout ----
    // Front region (dead before aggregate runs): counts/scan/binned.
    int*  counts    = (int*)d_ws;                 // SC_PAD
    int*  blockSums = counts + SC_PAD;            // 256
    int*  blockOff  = blockSums + 256;            // 256
    int*  scanned   = blockOff + 256;             // SC_PAD
    int2* binned    = (int2*)(scanned + SC_PAD);  // N_EDGES int2 (12.8 MB)
    // agg ALIASES the front region (25.6 MB from ws start covers it all);
    // binned/counts/scanned are dead once nodeSort completes.
    float* agg      = (float*)d_ws;               // N_NODES*IN_DIM floats
    // Persistent region beyond 25.6 MB:
    int*   sortedSrc = (int*)((char*)d_ws + (size_t)N_NODES * IN_DIM * sizeof(float));
    int*   offsets   = sortedSrc + N_EDGES;       // N_NODES+1 (+1 pad)
    float* gsum      = (float*)(offsets + N_NODES + 2);
    float* gsq       = gsum + HID;
    float* scale     = gsq + HID;
    float* shift     = scale + HID;

    hipMemsetAsync(counts, 0, SC_PAD * sizeof(int), stream);
    hipMemsetAsync(gsum, 0, 2 * HID * sizeof(float), stream);

    binCount_kernel<<<BC_BLOCKS, 256, 0, stream>>>(dst, counts);
    scanA_kernel<<<SC_NBLK, 256, 0, stream>>>(counts, blockSums);
    scanB_kernel<<<1, 256, 0, stream>>>(blockSums, blockOff);
    scanC_kernel<<<SC_NBLK, 256, 0, stream>>>(counts, blockOff, scanned);
    binPlace_kernel<<<BC_BLOCKS, 256, 0, stream>>>(src, dst, scanned, binned);
    nodeSort_kernel<<<NB, 256, 0, stream>>>(binned, scanned, sortedSrc, offsets);
    aggregate_kernel<<<(N_NODES * 64 + 255) / 256, 256, 0, stream>>>(h, sortedSrc,
                                                                     offsets, agg);
    gemm_stats_kernel<<<N_NODES / ROWS, 256, 0, stream>>>(agg, W, b, z, gsum, gsq);
    finalize_kernel<<<1, HID, 0, stream>>>(gsum, gsq, gamma, beta, scale, shift,
                                           1.0f / (float)N_NODES);
    norm_kernel<<<2048, 256, 0, stream>>>(z, scale, shift, N_NODES * HID / 4);
}

// Round 4
// 194.240 us; speedup vs baseline: 2.4464x; 1.2872x over previous
//
#include <hip/hip_runtime.h>

#define N_NODES 100000
#define N_EDGES 1600000
#define IN_DIM  64
#define HID     128
#define BN_EPS  1e-5f

// two-level counting sort geometry
#define NB        782      // coarse buckets: dst>>7
#define BC_BLOCKS 196      // binning blocks, 8192 edges each
#define EPB4      2048     // int4s per binning block
#define SC_PAD    153600   // NB*BC_BLOCKS=153272 padded
#define SC_NBLK   150

// syrk geometry
#define SYRK_BLOCKS 256
#define SYRK_ROWS   391    // 256*391 = 100096 >= N_NODES
#define GSZ         4160   // 64*64 G + 64 colsum

// ---------------- 1. per-(bucket,block) counts via LDS histogram ----------------
__global__ __launch_bounds__(256) void binCount_kernel(const int* __restrict__ dst,
                                                       int* __restrict__ counts)
{
    __shared__ int hist[NB];
    const int t = threadIdx.x, blk = blockIdx.x;
    for (int i = t; i < NB; i += 256) hist[i] = 0;
    __syncthreads();
    const int4* d4 = (const int4*)dst;
    const int base = blk * EPB4;
#pragma unroll
    for (int it = 0; it < 8; ++it) {
        int i = base + it * 256 + t;
        if (i < N_EDGES / 4) {
            int4 v = d4[i];
            atomicAdd(&hist[v.x >> 7], 1);
            atomicAdd(&hist[v.y >> 7], 1);
            atomicAdd(&hist[v.z >> 7], 1);
            atomicAdd(&hist[v.w >> 7], 1);
        }
    }
    __syncthreads();
    for (int i = t; i < NB; i += 256) counts[i * BC_BLOCKS + blk] = hist[i];
}

// ---------------- 2. hierarchical exclusive scan of counts ----------------
__global__ __launch_bounds__(256) void scanA_kernel(const int* __restrict__ counts,
                                                    int* __restrict__ blockSums)
{
    __shared__ int lds[256];
    int t = threadIdx.x;
    int4 v = ((const int4*)counts)[blockIdx.x * 256 + t];
    lds[t] = v.x + v.y + v.z + v.w;
    __syncthreads();
    for (int off = 128; off > 0; off >>= 1) {
        if (t < off) lds[t] += lds[t + off];
        __syncthreads();
    }
    if (t == 0) blockSums[blockIdx.x] = lds[0];
}

__global__ __launch_bounds__(256) void scanB_kernel(const int* __restrict__ blockSums,
                                                    int* __restrict__ blockOff)
{
    __shared__ int lds[256];
    int t = threadIdx.x;
    int v = (t < SC_NBLK) ? blockSums[t] : 0;
    lds[t] = v;
    __syncthreads();
    for (int off = 1; off < 256; off <<= 1) {
        int u = (t >= off) ? lds[t - off] : 0;
        __syncthreads();
        lds[t] += u;
        __syncthreads();
    }
    if (t < SC_NBLK) blockOff[t] = lds[t] - v;
}

__global__ __launch_bounds__(256) void scanC_kernel(const int* __restrict__ counts,
                                                    const int* __restrict__ blockOff,
                                                    int* __restrict__ scanned)
{
    __shared__ int lds[256];
    int t = threadIdx.x;
    int idx = blockIdx.x * 256 + t;
    int4 v = ((const int4*)counts)[idx];
    int tsum = v.x + v.y + v.z + v.w;
    lds[t] = tsum;
    __syncthreads();
    for (int off = 1; off < 256; off <<= 1) {
        int u = (t >= off) ? lds[t - off] : 0;
        __syncthreads();
        lds[t] += u;
        __syncthreads();
    }
    int base = blockOff[blockIdx.x] + lds[t] - tsum;
    int i0 = idx * 4;
    scanned[i0 + 0] = base;
    scanned[i0 + 1] = base + v.x;
    scanned[i0 + 2] = base + v.x + v.y;
    scanned[i0 + 3] = base + v.x + v.y + v.z;
}

// ---------------- 3. place (src,dst) into coarse buckets ----------------
__global__ __launch_bounds__(256) void binPlace_kernel(const int* __restrict__ src,
                                                       const int* __restrict__ dst,
                                                       const int* __restrict__ scanned,
                                                       int2* __restrict__ binned)
{
    __shared__ int cur[NB];
    const int t = threadIdx.x, blk = blockIdx.x;
    for (int i = t; i < NB; i += 256) cur[i] = scanned[i * BC_BLOCKS + blk];
    __syncthreads();
    const int4* d4 = (const int4*)dst;
    const int4* s4 = (const int4*)src;
    const int base = blk * EPB4;
#pragma unroll
    for (int it = 0; it < 8; ++it) {
        int i = base + it * 256 + t;
        if (i < N_EDGES / 4) {
            int4 dv = d4[i];
            int4 sv = s4[i];
            int p0 = atomicAdd(&cur[dv.x >> 7], 1); binned[p0] = make_int2(sv.x, dv.x);
            int p1 = atomicAdd(&cur[dv.y >> 7], 1); binned[p1] = make_int2(sv.y, dv.y);
            int p2 = atomicAdd(&cur[dv.z >> 7], 1); binned[p2] = make_int2(sv.z, dv.z);
            int p3 = atomicAdd(&cur[dv.w >> 7], 1); binned[p3] = make_int2(sv.w, dv.w);
        }
    }
}

// ---------------- 4. within-bucket sort -> CSR offsets + sortedSrc ----------------
__global__ __launch_bounds__(256) void nodeSort_kernel(const int2* __restrict__ binned,
                                                       const int* __restrict__ scanned,
                                                       int* __restrict__ sortedSrc,
                                                       int* __restrict__ offsets)
{
    __shared__ int hist[128];
    __shared__ int sc[128];
    __shared__ int cur[128];
    const int b = blockIdx.x, t = threadIdx.x;
    const int beg = scanned[b * BC_BLOCKS];
    const int end = scanned[(b + 1) * BC_BLOCKS];
    if (t < 128) hist[t] = 0;
    __syncthreads();
    for (int i = beg + t; i < end; i += 256)
        atomicAdd(&hist[binned[i].y & 127], 1);
    __syncthreads();
    int v = (t < 128) ? hist[t] : 0;
    if (t < 128) sc[t] = v;
    __syncthreads();
    for (int off = 1; off < 128; off <<= 1) {
        int u = (t < 128 && t >= off) ? sc[t - off] : 0;
        __syncthreads();
        if (t < 128) sc[t] += u;
        __syncthreads();
    }
    if (t < 128) {
        int excl = beg + sc[t] - v;
        cur[t] = excl;
        int node = (b << 7) + t;
        if (node < N_NODES) offsets[node] = excl;
    }
    if (b == NB - 1 && t == 0) offsets[N_NODES] = N_EDGES;
    __syncthreads();
    for (int i = beg + t; i < end; i += 256) {
        int2 p = binned[i];
        int pos = atomicAdd(&cur[p.y & 127], 1);
        sortedSrc[pos] = p.x;
    }
}

// ---------------- 5. aggregate: one wave per node, lane = feature ----------------
__global__ __launch_bounds__(256) void aggregate_kernel(
    const float* __restrict__ h, const int* __restrict__ sortedSrc,
    const int* __restrict__ offsets, float* __restrict__ agg)
{
    int wave = (blockIdx.x * 256 + threadIdx.x) >> 6;
    int lane = threadIdx.x & 63;
    if (wave >= N_NODES) return;
    int beg = offsets[wave];
    int end = offsets[wave + 1];
    float acc = 0.f;
    for (int i = beg; i < end; i += 64) {
        int cnt = end - i; if (cnt > 64) cnt = 64;
        int sv = (lane < cnt) ? sortedSrc[i + lane] : 0;
        int j = 0;
        for (; j + 4 <= cnt; j += 4) {
            int s0 = __shfl(sv, j + 0);
            int s1 = __shfl(sv, j + 1);
            int s2 = __shfl(sv, j + 2);
            int s3 = __shfl(sv, j + 3);
            float v0 = h[s0 * IN_DIM + lane];
            float v1 = h[s1 * IN_DIM + lane];
            float v2 = h[s2 * IN_DIM + lane];
            float v3 = h[s3 * IN_DIM + lane];
            acc += v0; acc += v1; acc += v2; acc += v3;
        }
        for (; j < cnt; ++j) {
            int s = __shfl(sv, j);
            acc += h[s * IN_DIM + lane];
        }
    }
    agg[(size_t)wave * IN_DIM + lane] = acc;
}

// ---------------- 6. syrk: G-partials = agg^T agg, colsum partials ----------------
__global__ __launch_bounds__(256) void syrk_kernel(const float* __restrict__ agg,
                                                   float* __restrict__ Gp)
{
    __shared__ float As[32][64];
    const int t = threadIdx.x, blk = blockIdx.x;
    const int row_beg = blk * SYRK_ROWS;
    int row_end = row_beg + SYRK_ROWS;
    if (row_end > N_NODES) row_end = N_NODES;

    const int i0 = (t & 15) * 4, j0 = (t >> 4) * 4;
    float acc[4][4];
#pragma unroll
    for (int i = 0; i < 4; i++)
#pragma unroll
        for (int j = 0; j < 4; j++) acc[i][j] = 0.f;
    float cs = 0.f;

    for (int r0 = row_beg; r0 < row_end; r0 += 32) {
        int nrows = row_end - r0; if (nrows > 32) nrows = 32;
        for (int i = t; i < nrows * 16; i += 256)
            ((float4*)&As[0][0])[i] = ((const float4*)(agg + (size_t)r0 * IN_DIM))[i];
        __syncthreads();
        for (int r = 0; r < nrows; ++r) {
            float4 ai = *(const float4*)&As[r][i0];
            float4 aj = *(const float4*)&As[r][j0];
            acc[0][0] += ai.x * aj.x; acc[0][1] += ai.x * aj.y;
            acc[0][2] += ai.x * aj.z; acc[0][3] += ai.x * aj.w;
            acc[1][0] += ai.y * aj.x; acc[1][1] += ai.y * aj.y;
            acc[1][2] += ai.y * aj.z; acc[1][3] += ai.y * aj.w;
            acc[2][0] += ai.z * aj.x; acc[2][1] += ai.z * aj.y;
            acc[2][2] += ai.z * aj.z; acc[2][3] += ai.z * aj.w;
            acc[3][0] += ai.w * aj.x; acc[3][1] += ai.w * aj.y;
            acc[3][2] += ai.w * aj.z; acc[3][3] += ai.w * aj.w;
        }
        if (t < 64) {
            for (int r = 0; r < nrows; ++r) cs += As[r][t];
        }
        __syncthreads();
    }
    float* gp = Gp + (size_t)blk * GSZ;
#pragma unroll
    for (int i = 0; i < 4; i++)
#pragma unroll
        for (int j = 0; j < 4; j++)
            gp[(i0 + i) * 64 + (j0 + j)] = acc[i][j];
    if (t < 64) gp[4096 + t] = cs;
}

// ---------------- 7. reduce G partials ----------------
__global__ __launch_bounds__(256) void reduceG_kernel(const float* __restrict__ Gp,
                                                      float* __restrict__ G)
{
    int gid = blockIdx.x * 256 + threadIdx.x;
    if (gid < GSZ) {
        float s = 0.f;
        for (int b = 0; b < SYRK_BLOCKS; ++b) s += Gp[(size_t)b * GSZ + gid];
        G[gid] = s;
    }
}

// ---------------- 8. finalize: per-column scale/shift from G ----------------
__global__ __launch_bounds__(256) void finalize_kernel(
    const float* __restrict__ G, const float* __restrict__ W,
    const float* __restrict__ bias, const float* __restrict__ gamma,
    const float* __restrict__ beta, float* __restrict__ scale,
    float* __restrict__ shift)
{
    __shared__ float Gs[4096];
    __shared__ float ss[64];
    __shared__ float part[256];
    const int t = threadIdx.x;
    for (int i = t; i < 4096; i += 256) Gs[i] = G[i];
    if (t < 64) ss[t] = G[4096 + t];
    __syncthreads();

    const int c = t & 127, half = t >> 7;
    float wc[64];
#pragma unroll
    for (int k = 0; k < 64; ++k) wc[k] = W[k * HID + c];

    float p = 0.f;
    for (int k1 = 0; k1 < 32; ++k1) {
        int k1g = half * 32 + k1;
        float dot = 0.f;
#pragma unroll
        for (int k2 = 0; k2 < 64; ++k2) dot += Gs[k1g * 64 + k2] * wc[k2];
        p += W[k1g * HID + c] * dot;  // reload (L1-hot) to keep wc statically indexed
    }
    part[t] = p;
    __syncthreads();
    if (half == 0) {
        float quad = part[c] + part[c + 128];  // w_c^T G w_c
        float tc = 0.f;
#pragma unroll
        for (int k = 0; k < 64; ++k) tc += ss[k] * wc[k];
        const float invN = 1.0f / (float)N_NODES;
        float bc   = bias[c];
        float mean = tc * invN + bc;
        float ez2  = quad * invN + 2.f * bc * tc * invN + bc * bc;
        float var  = ez2 - mean * mean;
        float inv  = rsqrtf(var + BN_EPS);
        float scv  = gamma[c] * inv;
        scale[c] = scv;
        shift[c] = beta[c] - mean * scv;
    }
}

// ---------------- 9. fused GEMM + scale/shift, single output write ----------------
__global__ __launch_bounds__(256) void gemm_out_kernel(
    const float* __restrict__ agg, const float* __restrict__ W,
    const float* __restrict__ scale, const float* __restrict__ shift,
    float* __restrict__ out, int n_blocks)
{
    __shared__ float As[32][64];
    __shared__ float sS[HID], sH[HID];
    const int t = threadIdx.x;
    const int lane = t & 63, wv = t >> 6;
    if (t < HID) { sS[t] = scale[t]; sH[t] = shift[t]; }

    // W into registers: lane owns cols 2*lane, 2*lane+1
    float2 wr[64];
#pragma unroll
    for (int k = 0; k < 64; ++k) wr[k] = ((const float2*)W)[k * 64 + lane];
    __syncthreads();

    for (int tile = blockIdx.x; tile < N_NODES / 32; tile += n_blocks) {
        const int r0 = tile * 32;
        for (int i = t; i < 512; i += 256)
            ((float4*)&As[0][0])[i] = ((const float4*)(agg + (size_t)r0 * IN_DIM))[i];
        __syncthreads();
        const int rbeg = wv * 8;
        for (int r = rbeg; r < rbeg + 8; ++r) {
            const float4* arow = (const float4*)&As[r][0];
            float a0 = 0.f, a1 = 0.f;
#pragma unroll
            for (int kk = 0; kk < 16; ++kk) {
                float4 a = arow[kk];
                a0 += a.x * wr[4 * kk + 0].x; a1 += a.x * wr[4 * kk + 0].y;
                a0 += a.y * wr[4 * kk + 1].x; a1 += a.y * wr[4 * kk + 1].y;
                a0 += a.z * wr[4 * kk + 2].x; a1 += a.z * wr[4 * kk + 2].y;
                a0 += a.w * wr[4 * kk + 3].x; a1 += a.w * wr[4 * kk + 3].y;
            }
            const int c0 = lane * 2;
            float o0 = a0 * sS[c0]     + sH[c0];
            float o1 = a1 * sS[c0 + 1] + sH[c0 + 1];
            ((float2*)out)[(size_t)(r0 + r) * 64 + lane] = make_float2(o0, o1);
        }
        __syncthreads();
    }
}

extern "C" void kernel_launch(void* const* d_in, const int* in_sizes, int n_in,
                              void* d_out, int out_size, void* d_ws, size_t ws_size,
                              hipStream_t stream)
{
    const float* h     = (const float*)d_in[0];
    const int*   src   = (const int*)d_in[1];
    const int*   dst   = (const int*)d_in[2];
    const float* W     = (const float*)d_in[3];
    const float* b     = (const float*)d_in[4];
    const float* gamma = (const float*)d_in[5];
    const float* beta  = (const float*)d_in[6];

    float* out = (float*)d_out;

    // ---- workspace layout ----
    // Front region (dead before aggregate): counts/scan/binned; agg aliases it.
    int*  counts    = (int*)d_ws;                 // SC_PAD
    int*  blockSums = counts + SC_PAD;            // 256
    int*  blockOff  = blockSums + 256;            // 256
    int*  scanned   = blockOff + 256;             // SC_PAD
    int2* binned    = (int2*)(scanned + SC_PAD);  // N_EDGES int2 (12.8 MB, < 25.6 MB)
    float* agg      = (float*)d_ws;               // N_NODES*IN_DIM floats (25.6 MB)
    // Persistent region beyond 25.6 MB:
    int*   sortedSrc = (int*)((char*)d_ws + (size_t)N_NODES * IN_DIM * sizeof(float));
    int*   offsets   = sortedSrc + N_EDGES;       // N_NODES+1 (+pad)
    float* Gp        = (float*)(offsets + N_NODES + 2);   // SYRK_BLOCKS*GSZ
    float* G         = Gp + (size_t)SYRK_BLOCKS * GSZ;    // GSZ
    float* scale     = G + GSZ;                           // HID
    float* shift     = scale + HID;                       // HID

    hipMemsetAsync(counts, 0, SC_PAD * sizeof(int), stream);

    binCount_kernel<<<BC_BLOCKS, 256, 0, stream>>>(dst, counts);
    scanA_kernel<<<SC_NBLK, 256, 0, stream>>>(counts, blockSums);
    scanB_kernel<<<1, 256, 0, stream>>>(blockSums, blockOff);
    scanC_kernel<<<SC_NBLK, 256, 0, stream>>>(counts, blockOff, scanned);
    binPlace_kernel<<<BC_BLOCKS, 256, 0, stream>>>(src, dst, scanned, binned);
    nodeSort_kernel<<<NB, 256, 0, stream>>>(binned, scanned, sortedSrc, offsets);
    aggregate_kernel<<<(N_NODES * 64 + 255) / 256, 256, 0, stream>>>(h, sortedSrc,
                                                                     offsets, agg);
    syrk_kernel<<<SYRK_BLOCKS, 256, 0, stream>>>(agg, Gp);
    reduceG_kernel<<<(GSZ + 255) / 256, 256, 0, stream>>>(Gp, G);
    finalize_kernel<<<1, 256, 0, stream>>>(G, W, b, gamma, beta, scale, shift);
    gemm_out_kernel<<<512, 256, 0, stream>>>(agg, W, scale, shift, out, 512);
}